// Round 6
// baseline (1174.307 us; speedup 1.0000x reference)
//
#include <hip/hip_runtime.h>

#define N_NODES 50000
#define N_FEAT  128
#define HID     64
#define N_EDGES 1600000
#define LN_EPS  1e-5f
#define NB2     400          // bins per side
#define BW2     125          // nodes per bin (400*125 = 50000)
#define CAP2    5120u        // per-bin record capacity (mean 4000, +17 sigma)

typedef unsigned int uint;

__device__ __forceinline__ float bcastf(float v, int l){
  return __uint_as_float(__builtin_amdgcn_readlane(__float_as_uint(v), l));
}
// int8-quantized row accumulate: a[i] += s * u8[i]  (bias 128 corrected later via ssum)
__device__ __forceinline__ void accq8(float* a, uint2 v, float s){
  a[0] = fmaf(s, (float)( v.x         & 0xffu), a[0]);
  a[1] = fmaf(s, (float)((v.x >> 8)   & 0xffu), a[1]);
  a[2] = fmaf(s, (float)((v.x >> 16)  & 0xffu), a[2]);
  a[3] = fmaf(s, (float)( v.x >> 24          ), a[3]);
  a[4] = fmaf(s, (float)( v.y         & 0xffu), a[4]);
  a[5] = fmaf(s, (float)((v.y >> 8)   & 0xffu), a[5]);
  a[6] = fmaf(s, (float)((v.y >> 16)  & 0xffu), a[6]);
  a[7] = fmaf(s, (float)( v.y >> 24          ), a[7]);
}

// ---------------- precompute: Wc = Wpsi @ W, bc = combined bias, zero pad scales --------
__global__ void prep_kernel(const float* __restrict__ Wpp, const float* __restrict__ Wp,
                            const float* __restrict__ Wpn, const float* __restrict__ Wn,
                            const float* __restrict__ bp, const float* __restrict__ bpp,
                            const float* __restrict__ bn, const float* __restrict__ bpn,
                            float* __restrict__ Wc_p, float* __restrict__ Wc_n,
                            float* __restrict__ bc,
                            float* __restrict__ sc_p, float* __restrict__ sc_n){
  int idx = blockIdx.x * blockDim.x + threadIdx.x;
  if (idx < 4096){
    int j = idx >> 6, k = idx & 63;
    float sp = 0.f, sn = 0.f;
    for (int m = 0; m < 64; ++m){
      sp += Wpp[j * 64 + m] * Wp[m * 64 + k];
      sn += Wpn[j * 64 + m] * Wn[m * 64 + k];
    }
    Wc_p[idx] = sp; Wc_n[idx] = sn;
  } else if (idx < 4160){
    int j = idx - 4096;
    float s = bpp[j] + bpn[j];
    for (int m = 0; m < 64; ++m) s += Wpp[j * 64 + m] * bp[m] + Wpn[j * 64 + m] * bn[m];
    bc[j] = s;
  } else if (idx == 4160){
    sc_p[N_NODES] = 0.f;        // pad-row scale -> pad contributes exactly 0
    sc_n[N_NODES] = 0.f;
  }
}

// ---------------- phase A: bin edges by dst range (400 bins/side) ----------------
__global__ __launch_bounds__(256) void binA_kernel(
    const int* __restrict__ ep, const int* __restrict__ en,
    uint* __restrict__ bin_cur, uint* __restrict__ recs_p, uint* __restrict__ recs_n){
  __shared__ uint sh[8192];
  __shared__ uint cnt2[NB2], gb2[NB2], rnk2[NB2];
  const int NBLK = (N_EDGES + 8191) / 8192;
  int bid = blockIdx.x;
  int side = bid >= NBLK;
  const int* e = side ? en : ep;
  uint* recs = side ? recs_n : recs_p;
  uint* bcur = bin_cur + side * NB2;
  int cbase = (side ? bid - NBLK : bid) * 8192;
  int tid = threadIdx.x;
  for (int i = tid; i < NB2; i += 256){ cnt2[i] = 0; rnk2[i] = 0; }
  __syncthreads();
  for (int i = tid; i < 8192; i += 256){
    int t = cbase + i;
    uint r = 0xFFFFFFFFu;
    if (t < N_EDGES){
      uint s = (uint)e[t], d = (uint)e[N_EDGES + t];
      r = (d << 16) | s;
      atomicAdd(&cnt2[d / BW2], 1u);
    }
    sh[i] = r;
  }
  __syncthreads();
  for (int i = tid; i < NB2; i += 256) gb2[i] = atomicAdd(&bcur[i], cnt2[i]);
  __syncthreads();
  for (int i = tid; i < 8192; i += 256){
    uint r = sh[i];
    if (r != 0xFFFFFFFFu){
      uint b = (r >> 16) / BW2;
      uint pos = gb2[b] + atomicAdd(&rnk2[b], 1u);
      recs[b * CAP2 + pos] = r;
    }
  }
}

// ---------------- LDS-staged counting sort per bin: cnt, dinv, cs (coalesced) ------------
__global__ __launch_bounds__(256) void fillC_kernel(
    const uint* __restrict__ bin_cur,
    const uint* __restrict__ recs_p, const uint* __restrict__ recs_n,
    int* __restrict__ cnt_p, int* __restrict__ cnt_n,
    float* __restrict__ dinv_p, float* __restrict__ dinv_n,
    unsigned short* __restrict__ cs_p, unsigned short* __restrict__ cs_n){
  __shared__ int hist[128];
  __shared__ int curx[128];
  __shared__ unsigned short staged[CAP2];
  __shared__ uint base_s;
  int bid = blockIdx.x;
  int side = bid >= NB2; int b = side ? bid - NB2 : bid;
  const uint* recs = (side ? recs_n : recs_p) + (size_t)b * CAP2;
  int* cnt = side ? cnt_n : cnt_p;
  float* dinv = side ? dinv_n : dinv_p;
  unsigned short* cs = side ? cs_n : cs_p;
  int tid = threadIdx.x, lane = tid & 63, wid = tid >> 6;
  int nodebase = b * BW2;
  if (tid < 128) hist[tid] = 0;
  __syncthreads();
  uint n = bin_cur[side * NB2 + b];
  if (wid == 1){
    uint s = 0;
    for (int k = lane; k < b; k += 64) s += bin_cur[side * NB2 + k];
    #pragma unroll
    for (int d = 1; d < 64; d <<= 1) s += __shfl_xor(s, d);
    if (lane == 0) base_s = s;
  }
  for (uint i = tid; i < n; i += 256)
    atomicAdd(&hist[(recs[i] >> 16) - nodebase], 1);
  __syncthreads();
  if (tid < BW2){
    int c = hist[tid];
    cnt[nodebase + tid] = c;
    dinv[nodebase + tid] = rsqrtf((float)(c + 1));
  }
  if (wid == 0){
    int carry = 0;
    #pragma unroll
    for (int base = 0; base < BW2; base += 64){
      int idx = base + lane;
      int v = (idx < BW2) ? hist[idx] : 0;
      int x = v;
      #pragma unroll
      for (int d = 1; d < 64; d <<= 1){
        int y = __shfl_up(x, d);
        if (lane >= d) x += y;
      }
      if (idx < BW2) curx[idx] = carry + x - v;
      int tot = __shfl(x, 63);
      carry = carry + tot;
    }
  }
  __syncthreads();
  for (uint i = tid; i < n; i += 256){
    uint r = recs[i];
    int d = (int)(r >> 16) - nodebase;
    int p = atomicAdd(&curx[d], 1);
    staged[p] = (unsigned short)(r & 0xFFFFu);
  }
  __syncthreads();
  uint base = base_s;
  for (uint i = tid; i < n; i += 256) cs[base + i] = staged[i];
}

// ---------------- per-side scan of cnt -> off (16 blocks: side*8+segment) ----------------
__global__ __launch_bounds__(1024) void scan16_kernel(
    const uint* __restrict__ bin_cur,
    const int* __restrict__ c0, int* __restrict__ o0,
    const int* __restrict__ c1, int* __restrict__ o1){
  __shared__ int wsum[16];
  __shared__ int wexcl[16];
  __shared__ int carry_s;
  int side = blockIdx.x >> 3, b = blockIdx.x & 7;
  const int* c = side ? c1 : c0;
  int* o = side ? o1 : o0;
  int tid = threadIdx.x, lane = tid & 63, wid = tid >> 6;
  if (wid == 0){
    int s = 0;
    for (int k = lane; k < 50 * b; k += 64) s += (int)bin_cur[side * NB2 + k];
    #pragma unroll
    for (int d = 1; d < 64; d <<= 1) s += __shfl_xor(s, d);
    if (lane == 0) carry_s = s;
  }
  __syncthreads();
  int lo = b * 6250, hi = lo + 6250;
  for (int base = lo; base < hi; base += 1024){
    int idx = base + tid;
    int v = (idx < hi) ? c[idx] : 0;
    int x = v;
    #pragma unroll
    for (int d = 1; d < 64; d <<= 1){
      int y = __shfl_up(x, d);
      if (lane >= d) x += y;
    }
    if (lane == 63) wsum[wid] = x;
    __syncthreads();
    int block_total = 0;
    if (tid == 0){
      int s = 0;
      for (int wv = 0; wv < 16; ++wv){ wexcl[wv] = s; s += wsum[wv]; }
      block_total = s;
    }
    __syncthreads();
    if (idx < hi) o[idx] = carry_s + wexcl[wid] + (x - v);
    __syncthreads();
    if (tid == 0) carry_s += block_total;
    __syncthreads();
  }
  if (b == 7 && tid == 0) o[N_NODES] = carry_s;
}

// ---------------- encoder: hbase = x@Wenc^T+b; hn = LN(hbase). Weights in VGPRs ----------
__global__ __launch_bounds__(256) void enc_kernel(
    const float* __restrict__ x, const float* __restrict__ Wenc, const float* __restrict__ benc,
    const float* __restrict__ gamma, const float* __restrict__ beta,
    float* __restrict__ hbase, float* __restrict__ hn){
  int lane = threadIdx.x & 63, wid = threadIdx.x >> 6;
  float we[128];
  const float* wr = Wenc + lane * N_FEAT;
  #pragma unroll
  for (int k4 = 0; k4 < 32; ++k4){
    float4 v = *(const float4*)(wr + 4 * k4);
    we[4*k4] = v.x; we[4*k4+1] = v.y; we[4*k4+2] = v.z; we[4*k4+3] = v.w;
  }
  float bv = benc[lane], g = gamma[lane], bt = beta[lane];
  int gw = blockIdx.x * 4 + wid, nw = gridDim.x * 4;
  for (int p = gw; p < N_NODES / 2; p += nw){
    int n0 = 2 * p, n1 = n0 + 1;
    float xa0 = x[(size_t)n0 * N_FEAT + lane], xb0 = x[(size_t)n0 * N_FEAT + 64 + lane];
    float xa1 = x[(size_t)n1 * N_FEAT + lane], xb1 = x[(size_t)n1 * N_FEAT + 64 + lane];
    float h0 = bv, h1 = bv;
    #pragma unroll
    for (int k = 0; k < 64; ++k){
      h0 += bcastf(xa0, k) * we[k];
      h1 += bcastf(xa1, k) * we[k];
      h0 += bcastf(xb0, k) * we[64 + k];
      h1 += bcastf(xb1, k) * we[64 + k];
    }
    hbase[n0 * HID + lane] = h0;
    hbase[n1 * HID + lane] = h1;
    float s0 = h0, q0 = h0 * h0, s1 = h1, q1 = h1 * h1;
    #pragma unroll
    for (int d = 1; d < 64; d <<= 1){
      s0 += __shfl_xor(s0, d); q0 += __shfl_xor(q0, d);
      s1 += __shfl_xor(s1, d); q1 += __shfl_xor(q1, d);
    }
    float mu0 = s0 * (1.0f/64.0f), var0 = q0 * (1.0f/64.0f) - mu0 * mu0;
    float mu1 = s1 * (1.0f/64.0f), var1 = q1 * (1.0f/64.0f) - mu1 * mu1;
    hn[n0 * HID + lane] = (h0 - mu0) * rsqrtf(var0 + LN_EPS) * g + bt;
    hn[n1 * HID + lane] = (h1 - mu1) * rsqrtf(var1 + LN_EPS) * g + bt;
  }
}

// ---------------- conv: int8 rows + per-row scale. xq = u8(dinv*(hn@Wc^T)), sc = max/127 --
__global__ __launch_bounds__(256) void conv_kernel(
    const float* __restrict__ hn, const float* __restrict__ Wc_p, const float* __restrict__ Wc_n,
    const float* __restrict__ dinv_p, const float* __restrict__ dinv_n,
    unsigned char* __restrict__ xq_p, unsigned char* __restrict__ xq_n,
    float* __restrict__ sc_p, float* __restrict__ sc_n){
  int lane = threadIdx.x & 63, wid = threadIdx.x >> 6;
  float wp[64], wn[64];
  const float* wpr = Wc_p + lane * HID;
  const float* wnr = Wc_n + lane * HID;
  #pragma unroll
  for (int k4 = 0; k4 < 16; ++k4){
    float4 a = *(const float4*)(wpr + 4 * k4);
    wp[4*k4] = a.x; wp[4*k4+1] = a.y; wp[4*k4+2] = a.z; wp[4*k4+3] = a.w;
    float4 b = *(const float4*)(wnr + 4 * k4);
    wn[4*k4] = b.x; wn[4*k4+1] = b.y; wn[4*k4+2] = b.z; wn[4*k4+3] = b.w;
  }
  int gw = blockIdx.x * 4 + wid, nw = gridDim.x * 4;
  for (int p = gw; p < N_NODES / 2; p += nw){
    int n0 = 2 * p, n1 = n0 + 1;
    float h0 = hn[n0 * HID + lane], h1 = hn[n1 * HID + lane];
    float ap0 = 0.f, an0 = 0.f, ap1 = 0.f, an1 = 0.f;
    #pragma unroll
    for (int k = 0; k < 64; ++k){
      float a = bcastf(h0, k), b = bcastf(h1, k);
      ap0 += a * wp[k]; an0 += a * wn[k];
      ap1 += b * wp[k]; an1 += b * wn[k];
    }
    ap0 *= dinv_p[n0]; an0 *= dinv_n[n0];
    ap1 *= dinv_p[n1]; an1 *= dinv_n[n1];
    float mp0 = fabsf(ap0), mn0 = fabsf(an0), mp1 = fabsf(ap1), mn1 = fabsf(an1);
    #pragma unroll
    for (int d = 1; d < 64; d <<= 1){
      mp0 = fmaxf(mp0, __shfl_xor(mp0, d));
      mn0 = fmaxf(mn0, __shfl_xor(mn0, d));
      mp1 = fmaxf(mp1, __shfl_xor(mp1, d));
      mn1 = fmaxf(mn1, __shfl_xor(mn1, d));
    }
    float ep0 = (mp0 > 0.f) ? 127.0f / mp0 : 0.f;
    float en0 = (mn0 > 0.f) ? 127.0f / mn0 : 0.f;
    float ep1 = (mp1 > 0.f) ? 127.0f / mp1 : 0.f;
    float en1 = (mn1 > 0.f) ? 127.0f / mn1 : 0.f;
    xq_p[(size_t)n0 * 64 + lane] = (unsigned char)((int)rintf(ap0 * ep0) + 128);
    xq_n[(size_t)n0 * 64 + lane] = (unsigned char)((int)rintf(an0 * en0) + 128);
    xq_p[(size_t)n1 * 64 + lane] = (unsigned char)((int)rintf(ap1 * ep1) + 128);
    xq_n[(size_t)n1 * 64 + lane] = (unsigned char)((int)rintf(an1 * en1) + 128);
    if (lane == 0){
      sc_p[n0] = mp0 * (1.0f / 127.0f);
      sc_n[n0] = mn0 * (1.0f / 127.0f);
      sc_p[n1] = mp1 * (1.0f / 127.0f);
      sc_n[n1] = mn1 * (1.0f / 127.0f);
    }
  }
}

// ---------------- slow-path accumulate (deg > 64) --------------------
__device__ __forceinline__ void gather_side_acc(
    const unsigned char* __restrict__ xq, const float* __restrict__ sc,
    const unsigned short* __restrict__ cs,
    int s0, int s1, int g, int j8, int lane, float* acc, float& ssum){
  for (int base = s0; base < s1; base += 64){
    int jj = base + lane;
    int si = (jj < s1) ? (int)cs[jj] : N_NODES;
    int cnt = min(64, s1 - base);
    int nt = (cnt + 7) >> 3;
    for (int t = 0; t < nt; ++t){
      int r = __shfl(si, 8 * t + g);
      float s = sc[r];
      accq8(acc, *(const uint2*)(xq + (size_t)r * 64 + j8), s);
      ssum += s;
    }
  }
}

// ---------------- gather both sides, 2 nodes/wave + delta + RK4 + LN (fused) -------------
__global__ __launch_bounds__(256) void gatherrk_kernel(
    const unsigned char* __restrict__ xq_p, const unsigned char* __restrict__ xq_n,
    const float* __restrict__ sc_p, const float* __restrict__ sc_n,
    const unsigned short* __restrict__ cs_p, const int* __restrict__ off_p,
    const float* __restrict__ dinv_p,
    const unsigned short* __restrict__ cs_n, const int* __restrict__ off_n,
    const float* __restrict__ dinv_n,
    const float* __restrict__ bc, const float* __restrict__ gamma, const float* __restrict__ beta,
    const float* __restrict__ tvec,
    float* __restrict__ hbase, float* __restrict__ acc, float* __restrict__ hn,
    int st, int emit){
  int lane = threadIdx.x & 63, wid = threadIdx.x >> 6;
  int pair = blockIdx.x * 4 + wid;
  int nA = 2 * pair, nB = nA + 1;
  if (nA >= N_NODES) return;
  int g = lane >> 3, j = lane & 7, j8 = 8 * j, rowoff = j8;

  int pA0 = off_p[nA], pA1 = off_p[nA + 1], pB1 = off_p[nB + 1];
  int qA0 = off_n[nA], qA1 = off_n[nA + 1], qB1 = off_n[nB + 1];
  int dPA = pA1 - pA0, dPB = pB1 - pA1, dNA = qA1 - qA0, dNB = qB1 - qA1;

  float aPA[8] = {0,0,0,0,0,0,0,0};
  float aPB[8] = {0,0,0,0,0,0,0,0};
  float aNA[8] = {0,0,0,0,0,0,0,0};
  float aNB[8] = {0,0,0,0,0,0,0,0};
  float sPA = 0.f, sPB = 0.f, sNA = 0.f, sNB = 0.f;
  {   // self rows (group 0 real, other groups hit pad row with scale 0)
    int rA = (g == 0) ? nA : N_NODES;
    int rB = (g == 0) ? nB : N_NODES;
    float s0 = sc_p[rA], s1 = sc_p[rB], s2 = sc_n[rA], s3 = sc_n[rB];
    accq8(aPA, *(const uint2*)(xq_p + (size_t)rA * 64 + j8), s0); sPA += s0;
    accq8(aPB, *(const uint2*)(xq_p + (size_t)rB * 64 + j8), s1); sPB += s1;
    accq8(aNA, *(const uint2*)(xq_n + (size_t)rA * 64 + j8), s2); sNA += s2;
    accq8(aNB, *(const uint2*)(xq_n + (size_t)rB * 64 + j8), s3); sNB += s3;
  }

  if (dPA <= 64 && dPB <= 64 && dNA <= 64 && dNB <= 64){
    int siPA = (lane < dPA) ? (int)cs_p[pA0 + lane] : N_NODES;
    int siPB = (lane < dPB) ? (int)cs_p[pA1 + lane] : N_NODES;
    int siNA = (lane < dNA) ? (int)cs_n[qA0 + lane] : N_NODES;
    int siNB = (lane < dNB) ? (int)cs_n[qA1 + lane] : N_NODES;
    int dP = dPA > dPB ? dPA : dPB;
    int dN = dNA > dNB ? dNA : dNB;
    int ntP = (dP + 7) >> 3, ntN = (dN + 7) >> 3;
    for (int t = 0; t < ntP; t += 2){
      int gi0 = 8 * t + g, gi1 = gi0 + 8;
      int rA0 = __shfl(siPA, gi0), rB0 = __shfl(siPB, gi0);
      int rA1 = __shfl(siPA, gi1), rB1 = __shfl(siPB, gi1);
      float sA0 = sc_p[rA0], sB0 = sc_p[rB0], sA1 = sc_p[rA1], sB1 = sc_p[rB1];
      uint2 vA0 = *(const uint2*)(xq_p + (size_t)rA0 * 64 + j8);
      uint2 vB0 = *(const uint2*)(xq_p + (size_t)rB0 * 64 + j8);
      uint2 vA1 = *(const uint2*)(xq_p + (size_t)rA1 * 64 + j8);
      uint2 vB1 = *(const uint2*)(xq_p + (size_t)rB1 * 64 + j8);
      accq8(aPA, vA0, sA0); accq8(aPB, vB0, sB0);
      accq8(aPA, vA1, sA1); accq8(aPB, vB1, sB1);
      sPA += sA0 + sA1; sPB += sB0 + sB1;
    }
    for (int t = 0; t < ntN; t += 2){
      int gi0 = 8 * t + g, gi1 = gi0 + 8;
      int rA0 = __shfl(siNA, gi0), rB0 = __shfl(siNB, gi0);
      int rA1 = __shfl(siNA, gi1), rB1 = __shfl(siNB, gi1);
      float sA0 = sc_n[rA0], sB0 = sc_n[rB0], sA1 = sc_n[rA1], sB1 = sc_n[rB1];
      uint2 vA0 = *(const uint2*)(xq_n + (size_t)rA0 * 64 + j8);
      uint2 vB0 = *(const uint2*)(xq_n + (size_t)rB0 * 64 + j8);
      uint2 vA1 = *(const uint2*)(xq_n + (size_t)rA1 * 64 + j8);
      uint2 vB1 = *(const uint2*)(xq_n + (size_t)rB1 * 64 + j8);
      accq8(aNA, vA0, sA0); accq8(aNB, vB0, sB0);
      accq8(aNA, vA1, sA1); accq8(aNB, vB1, sB1);
      sNA += sA0 + sA1; sNB += sB0 + sB1;
    }
  } else {
    gather_side_acc(xq_p, sc_p, cs_p, pA0, pA1, g, j8, lane, aPA, sPA);
    gather_side_acc(xq_p, sc_p, cs_p, pA1, pB1, g, j8, lane, aPB, sPB);
    gather_side_acc(xq_n, sc_n, cs_n, qA0, qA1, g, j8, lane, aNA, sNA);
    gather_side_acc(xq_n, sc_n, cs_n, qA1, qB1, g, j8, lane, aNB, sNB);
  }
  // cross-group reduce sums and scale-sums
  sPA += __shfl_xor(sPA, 8); sPA += __shfl_xor(sPA, 16); sPA += __shfl_xor(sPA, 32);
  sPB += __shfl_xor(sPB, 8); sPB += __shfl_xor(sPB, 16); sPB += __shfl_xor(sPB, 32);
  sNA += __shfl_xor(sNA, 8); sNA += __shfl_xor(sNA, 16); sNA += __shfl_xor(sNA, 32);
  sNB += __shfl_xor(sNB, 8); sNB += __shfl_xor(sNB, 16); sNB += __shfl_xor(sNB, 32);
  #pragma unroll
  for (int i = 0; i < 8; ++i){
    float a = aPA[i]; a += __shfl_xor(a, 8); a += __shfl_xor(a, 16); a += __shfl_xor(a, 32);
    aPA[i] = a - 128.f * sPA;
    float b = aPB[i]; b += __shfl_xor(b, 8); b += __shfl_xor(b, 16); b += __shfl_xor(b, 32);
    aPB[i] = b - 128.f * sPB;
    float c = aNA[i]; c += __shfl_xor(c, 8); c += __shfl_xor(c, 16); c += __shfl_xor(c, 32);
    aNA[i] = c - 128.f * sNA;
    float d = aNB[i]; d += __shfl_xor(d, 8); d += __shfl_xor(d, 16); d += __shfl_xor(d, 32);
    aNB[i] = d - 128.f * sNB;
  }

  float dvpA = dinv_p[nA], dvnA = dinv_n[nA], dvpB = dinv_p[nB], dvnB = dinv_n[nB];
  float4 b0 = *(const float4*)(bc + rowoff);
  float4 b1 = *(const float4*)(bc + rowoff + 4);
  float bcv[8] = {b0.x, b0.y, b0.z, b0.w, b1.x, b1.y, b1.z, b1.w};

  size_t ixA = (size_t)nA * HID + rowoff, ixB = (size_t)nB * HID + rowoff;
  float4 hA0 = *(const float4*)(hbase + ixA), hA1 = *(const float4*)(hbase + ixA + 4);
  float4 hB0 = *(const float4*)(hbase + ixB), hB1 = *(const float4*)(hbase + ixB + 4);
  float hbA[8] = {hA0.x,hA0.y,hA0.z,hA0.w,hA1.x,hA1.y,hA1.z,hA1.w};
  float hbB[8] = {hB0.x,hB0.y,hB0.z,hB0.w,hB1.x,hB1.y,hB1.z,hB1.w};
  float avA[8], avB[8];
  if (st != 0){
    float4 aA0 = *(const float4*)(acc + ixA), aA1 = *(const float4*)(acc + ixA + 4);
    float4 aB0 = *(const float4*)(acc + ixB), aB1 = *(const float4*)(acc + ixB + 4);
    avA[0]=aA0.x; avA[1]=aA0.y; avA[2]=aA0.z; avA[3]=aA0.w;
    avA[4]=aA1.x; avA[5]=aA1.y; avA[6]=aA1.z; avA[7]=aA1.w;
    avB[0]=aB0.x; avB[1]=aB0.y; avB[2]=aB0.z; avB[3]=aB0.w;
    avB[4]=aB1.x; avB[5]=aB1.y; avB[6]=aB1.z; avB[7]=aB1.w;
  }
  float dt = (tvec[1] - tvec[0]) * 0.5f;
  float hvA[8], hvB[8];
  #pragma unroll
  for (int i = 0; i < 8; ++i){
    float dA = dvpA * aPA[i] + dvnA * aNA[i] + bcv[i];
    float dB = dvpB * aPB[i] + dvnB * aNB[i] + bcv[i];
    dA = fminf(fmaxf(dA, -50.f), 50.f);
    dB = fminf(fmaxf(dB, -50.f), 50.f);
    if (st == 0){
      avA[i] = dA; avB[i] = dB;
      hvA[i] = hbA[i] + 0.5f * dt * dA; hvB[i] = hbB[i] + 0.5f * dt * dB;
    } else if (st == 1){
      avA[i] += 2.0f * dA; avB[i] += 2.0f * dB;
      hvA[i] = hbA[i] + 0.5f * dt * dA; hvB[i] = hbB[i] + 0.5f * dt * dB;
    } else if (st == 2){
      avA[i] += 2.0f * dA; avB[i] += 2.0f * dB;
      hvA[i] = hbA[i] + dt * dA; hvB[i] = hbB[i] + dt * dB;
    } else {
      hvA[i] = hbA[i] + (dt * (1.0f/6.0f)) * (avA[i] + dA);
      hvB[i] = hbB[i] + (dt * (1.0f/6.0f)) * (avB[i] + dB);
    }
  }
  if (st < 3){
    if (g == 0){
      float4 o0 = {avA[0],avA[1],avA[2],avA[3]}, o1 = {avA[4],avA[5],avA[6],avA[7]};
      *(float4*)(acc + ixA) = o0; *(float4*)(acc + ixA + 4) = o1;
    } else if (g == 1){
      float4 o0 = {avB[0],avB[1],avB[2],avB[3]}, o1 = {avB[4],avB[5],avB[6],avB[7]};
      *(float4*)(acc + ixB) = o0; *(float4*)(acc + ixB + 4) = o1;
    }
  } else {
    if (g == 0){
      float4 o0 = {hvA[0],hvA[1],hvA[2],hvA[3]}, o1 = {hvA[4],hvA[5],hvA[6],hvA[7]};
      *(float4*)(hbase + ixA) = o0; *(float4*)(hbase + ixA + 4) = o1;
    } else if (g == 1){
      float4 o0 = {hvB[0],hvB[1],hvB[2],hvB[3]}, o1 = {hvB[4],hvB[5],hvB[6],hvB[7]};
      *(float4*)(hbase + ixB) = o0; *(float4*)(hbase + ixB + 4) = o1;
    }
  }
  if (emit){
    float sA = 0.f, qA = 0.f, sB = 0.f, qB = 0.f;
    #pragma unroll
    for (int i = 0; i < 8; ++i){
      sA += hvA[i]; qA += hvA[i] * hvA[i];
      sB += hvB[i]; qB += hvB[i] * hvB[i];
    }
    sA += __shfl_xor(sA, 1); qA += __shfl_xor(qA, 1);
    sA += __shfl_xor(sA, 2); qA += __shfl_xor(qA, 2);
    sA += __shfl_xor(sA, 4); qA += __shfl_xor(qA, 4);
    sB += __shfl_xor(sB, 1); qB += __shfl_xor(qB, 1);
    sB += __shfl_xor(sB, 2); qB += __shfl_xor(qB, 2);
    sB += __shfl_xor(sB, 4); qB += __shfl_xor(qB, 4);
    float muA = sA * (1.0f/64.0f), varA = qA * (1.0f/64.0f) - muA * muA;
    float muB = sB * (1.0f/64.0f), varB = qB * (1.0f/64.0f) - muB * muB;
    float rsA = rsqrtf(varA + LN_EPS), rsB = rsqrtf(varB + LN_EPS);
    float4 g0 = *(const float4*)(gamma + rowoff);
    float4 g1 = *(const float4*)(gamma + rowoff + 4);
    float4 t0 = *(const float4*)(beta + rowoff);
    float4 t1 = *(const float4*)(beta + rowoff + 4);
    float gm[8] = {g0.x,g0.y,g0.z,g0.w,g1.x,g1.y,g1.z,g1.w};
    float bt[8] = {t0.x,t0.y,t0.z,t0.w,t1.x,t1.y,t1.z,t1.w};
    if (g == 0){
      float4 o0, o1;
      o0.x=(hvA[0]-muA)*rsA*gm[0]+bt[0]; o0.y=(hvA[1]-muA)*rsA*gm[1]+bt[1];
      o0.z=(hvA[2]-muA)*rsA*gm[2]+bt[2]; o0.w=(hvA[3]-muA)*rsA*gm[3]+bt[3];
      o1.x=(hvA[4]-muA)*rsA*gm[4]+bt[4]; o1.y=(hvA[5]-muA)*rsA*gm[5]+bt[5];
      o1.z=(hvA[6]-muA)*rsA*gm[6]+bt[6]; o1.w=(hvA[7]-muA)*rsA*gm[7]+bt[7];
      *(float4*)(hn + ixA) = o0; *(float4*)(hn + ixA + 4) = o1;
    } else if (g == 1){
      float4 o0, o1;
      o0.x=(hvB[0]-muB)*rsB*gm[0]+bt[0]; o0.y=(hvB[1]-muB)*rsB*gm[1]+bt[1];
      o0.z=(hvB[2]-muB)*rsB*gm[2]+bt[2]; o0.w=(hvB[3]-muB)*rsB*gm[3]+bt[3];
      o1.x=(hvB[4]-muB)*rsB*gm[4]+bt[4]; o1.y=(hvB[5]-muB)*rsB*gm[5]+bt[5];
      o1.z=(hvB[6]-muB)*rsB*gm[6]+bt[6]; o1.w=(hvB[7]-muB)*rsB*gm[7]+bt[7];
      *(float4*)(hn + ixB) = o0; *(float4*)(hn + ixB + 4) = o1;
    }
  }
}

extern "C" void kernel_launch(void* const* d_in, const int* in_sizes, int n_in,
                              void* d_out, int out_size, void* d_ws, size_t ws_size,
                              hipStream_t stream){
  const float* x     = (const float*)d_in[0];
  const int*   ep    = (const int*)d_in[1];
  const int*   en    = (const int*)d_in[2];
  const float* tvec  = (const float*)d_in[3];
  const float* W_enc = (const float*)d_in[4];
  const float* b_enc = (const float*)d_in[5];
  const float* W_pos = (const float*)d_in[6];
  const float* b_pos = (const float*)d_in[7];
  const float* W_neg = (const float*)d_in[8];
  const float* b_neg = (const float*)d_in[9];
  const float* W_pp  = (const float*)d_in[10];
  const float* b_pp  = (const float*)d_in[11];
  const float* W_pn  = (const float*)d_in[12];
  const float* b_pn  = (const float*)d_in[13];
  const float* gamma = (const float*)d_in[14];
  const float* beta  = (const float*)d_in[15];
  float* hbase = (float*)d_out;

  char* w = (char*)d_ws;
  auto alloc = [&](size_t bytes) -> char* {
    char* p = w;
    w += (bytes + 255) & ~(size_t)255;
    return p;
  };
  uint*  bin_cur = (uint*)alloc(2 * NB2 * 4);
  int*   cnt_p = (int*)alloc(N_NODES * 4);
  int*   cnt_n = (int*)alloc(N_NODES * 4);
  int*   off_p = (int*)alloc((N_NODES + 1) * 4);
  int*   off_n = (int*)alloc((N_NODES + 1) * 4);
  float* dinv_p= (float*)alloc(N_NODES * 4);
  float* dinv_n= (float*)alloc(N_NODES * 4);
  uint*  recs_p= (uint*)alloc((size_t)NB2 * CAP2 * 4);
  uint*  recs_n= (uint*)alloc((size_t)NB2 * CAP2 * 4);
  unsigned short* cs_p = (unsigned short*)alloc((size_t)N_EDGES * 2);
  unsigned short* cs_n = (unsigned short*)alloc((size_t)N_EDGES * 2);
  unsigned char* xq_p = (unsigned char*)alloc((size_t)(N_NODES + 1) * 64);
  unsigned char* xq_n = (unsigned char*)alloc((size_t)(N_NODES + 1) * 64);
  float* sc_p  = (float*)alloc((N_NODES + 1) * 4);
  float* sc_n  = (float*)alloc((N_NODES + 1) * 4);
  float* hn    = (float*)alloc((size_t)N_NODES * HID * 4);
  float* accb  = (float*)alloc((size_t)N_NODES * HID * 4);
  float* Wc_p  = (float*)alloc(HID * HID * 4);
  float* Wc_n  = (float*)alloc(HID * HID * 4);
  float* bc    = (float*)alloc(HID * 4);

  hipMemsetAsync(bin_cur, 0, 2 * NB2 * 4, stream);

  dim3 blk(256);
  const int NBLK_A = 2 * ((N_EDGES + 8191) / 8192);
  prep_kernel<<<17, blk, 0, stream>>>(W_pp, W_pos, W_pn, W_neg, b_pos, b_pp, b_neg, b_pn,
                                      Wc_p, Wc_n, bc, sc_p, sc_n);
  binA_kernel<<<NBLK_A, blk, 0, stream>>>(ep, en, bin_cur, recs_p, recs_n);
  fillC_kernel<<<2 * NB2, blk, 0, stream>>>(bin_cur, recs_p, recs_n,
                                            cnt_p, cnt_n, dinv_p, dinv_n, cs_p, cs_n);
  scan16_kernel<<<16, 1024, 0, stream>>>(bin_cur, cnt_p, off_p, cnt_n, off_n);
  enc_kernel<<<1024, blk, 0, stream>>>(x, W_enc, b_enc, gamma, beta, hbase, hn);

  for (int s = 0; s < 8; ++s){
    conv_kernel<<<1024, blk, 0, stream>>>(hn, Wc_p, Wc_n, dinv_p, dinv_n,
                                          xq_p, xq_n, sc_p, sc_n);
    gatherrk_kernel<<<(N_NODES / 2 + 3) / 4, blk, 0, stream>>>(
        xq_p, xq_n, sc_p, sc_n, cs_p, off_p, dinv_p, cs_n, off_n, dinv_n,
        bc, gamma, beta, tvec, hbase, accb, hn, s & 3, (s < 7) ? 1 : 0);
  }
}